// Round 7
// baseline (118.082 us; speedup 1.0000x reference)
//
#include <hip/hip_runtime.h>
#include <math.h>

#define PROJ 8192
#define NB   16
#define NC   512
#define HW   196    // 14*14
#define KP   224    // K zero-padded to 7 chunks of 32
#define NKC  7

typedef __attribute__((ext_vector_type(8))) short bf16x8;   // MFMA A/B frag
typedef __attribute__((ext_vector_type(4))) float f32x4;    // MFMA C/D frag

__device__ __forceinline__ unsigned bf16_rne(float f) {
    unsigned u = __builtin_bit_cast(unsigned, f);
    return (u + 0x7fffu + ((u >> 16) & 1u)) >> 16;
}

// ---------------------------------------------------------------------------
// Kernel 0: pre-convert x -> sign-folded split-bf16, zero-padded K=224.
// X1h/X1l = s1-folded (A operand), X2h/X2l = s2-folded (B operand).
// Layout [b][c][kp] shorts (row stride 448 B, 16B-aligned). Each element
// converted ONCE, streaming. Arithmetic identical to baseline:
// hi=rne(s*x), lo=rne(s*x-hi); pad = 0. grid = 896 x 256.
// ---------------------------------------------------------------------------
__global__ __launch_bounds__(256)
void cbp_convert(const float* __restrict__ x,
                 const float* __restrict__ s1,
                 const float* __restrict__ s2,
                 short* __restrict__ X1h, short* __restrict__ X1l,
                 short* __restrict__ X2h, short* __restrict__ X2l) {
    const int v   = blockIdx.x * 256 + threadIdx.x;
    const int b   = v / (NC * 28);
    const int rem = v - b * (NC * 28);
    const int c   = rem / 28;
    const int g   = rem - c * 28;
    const int kk  = g * 8;

    const float* xs = x + ((size_t)b * NC + c) * HW;
    float4 f0 = {0.f,0.f,0.f,0.f}, f1 = {0.f,0.f,0.f,0.f};
    if (g < 24) {                       // rows are 784 B -> float4-aligned
        f0 = *(const float4*)(xs + kk);
        f1 = *(const float4*)(xs + kk + 4);
    } else if (g == 24) {
        f0 = *(const float4*)(xs + kk); // k=192..195; 196..199 stay zero
    }                                   // g>24: all pad
    const float w1 = s1[c], w2 = s2[c];
    const float f[8] = {f0.x, f0.y, f0.z, f0.w, f1.x, f1.y, f1.z, f1.w};
    bf16x8 h1v, l1v, h2v, l2v;
#pragma unroll
    for (int e = 0; e < 8; ++e) {
        const float a1 = f[e] * w1;
        const unsigned u1 = bf16_rne(a1);
        h1v[e] = (short)u1;
        l1v[e] = (short)bf16_rne(a1 - __builtin_bit_cast(float, u1 << 16));
        const float a2 = f[e] * w2;
        const unsigned u2 = bf16_rne(a2);
        h2v[e] = (short)u2;
        l2v[e] = (short)bf16_rne(a2 - __builtin_bit_cast(float, u2 << 16));
    }
    const size_t off = ((size_t)b * NC + c) * KP + kk;
    *(bf16x8*)(X1h + off) = h1v;
    *(bf16x8*)(X1l + off) = l1v;
    *(bf16x8*)(X2h + off) = h2v;
    *(bf16x8*)(X2l + off) = l2v;
}

// ---------------------------------------------------------------------------
// Kernel 1: Gram, pure load->MFMA. grid = 512 x 512 (8 waves), 128x64 output
// per block -> per wave only 2 A-frags + 2 B-frags, so the 2-deep double
// buffer is 8 bf16x8 = 64 VGPR and the whole kernel fits < 128 VGPR.
// __launch_bounds__(512,4) -> 2 blocks/CU = 4 waves/SIMD: R5's exposed
// per-fragment L2 latency (VGPR_Count=84 = collapsed dbuf, 2 waves/SIMD)
// now overlaps across waves. 2 barriers total.
//   blk -> (b, tile, jhalf): b = 2*(blk&7) + (blk>>8)   (XCD-pinned batch)
//                            mid = (blk>>3)&31, tile = mid>>1, jh = mid&1
// ---------------------------------------------------------------------------
__global__ __launch_bounds__(512, 4)
void cbp_gram(const short* __restrict__ X1h, const short* __restrict__ X1l,
              const short* __restrict__ X2h, const short* __restrict__ X2l,
              const int*   __restrict__ h1,  const int*   __restrict__ h2,
              float* __restrict__ ws) {
    __shared__ float sk[PROJ];         // 32 KB private sketch
    __shared__ int   lh1[128], lh2[64];

    const int tid = threadIdx.x;
    const int blk = blockIdx.x;
    const int b    = 2 * (blk & 7) + (blk >> 8);   // XCD-pinned batch
    const int mid  = (blk >> 3) & 31;
    const int tile = mid >> 1;
    const int jh   = mid & 1;
    const int c1base = (tile >> 2) * 128;
    const int c2base = (tile & 3) * 128 + jh * 64;

    const int lane = tid & 63;
    const int wave = tid >> 6;         // 0..7
    const int quad = lane >> 4;        // k-slot: k = kc*32 + quad*8 .. +7
    const int l15  = lane & 15;
    const int wr   = (wave >> 1) * 32; // wave's 32x32 sub-tile
    const int wc   = (wave & 1) * 32;

    for (int i = tid; i < PROJ; i += 512) sk[i] = 0.f;
    if (tid < 128) lh1[tid] = h1[c1base + tid];
    if (tid < 64)  lh2[tid] = h2[c2base + tid];

    // Per-lane fragment row pointers (hoisted; signs already folded).
    const short* pAh[2]; const short* pAl[2];
#pragma unroll
    for (int i = 0; i < 2; ++i) {
        const size_t r = (size_t)(b * NC + c1base + wr + i * 16 + l15) * KP;
        pAh[i] = X1h + r;  pAl[i] = X1l + r;
    }
    const short* pBh[2]; const short* pBl[2];
#pragma unroll
    for (int j = 0; j < 2; ++j) {
        const size_t r = (size_t)(b * NC + c2base + wc + j * 16 + l15) * KP;
        pBh[j] = X2h + r;  pBl[j] = X2l + r;
    }

    f32x4 acc[2][2];
#pragma unroll
    for (int i = 0; i < 2; ++i)
#pragma unroll
        for (int j = 0; j < 2; ++j) acc[i][j] = (f32x4){0.f, 0.f, 0.f, 0.f};

    bf16x8 buf[2][8];   // [parity][Ah0,Al0,Ah1,Al1,Bh0,Bl0,Bh1,Bl1] = 64 VGPR

#define LOADC(par, kc) do {                                                   \
    const int kk_ = (kc) * 32 + quad * 8;                                     \
    _Pragma("unroll") for (int i_ = 0; i_ < 2; ++i_) {                        \
        buf[par][2*i_]   = *(const bf16x8*)(pAh[i_] + kk_);                   \
        buf[par][2*i_+1] = *(const bf16x8*)(pAl[i_] + kk_); }                 \
    _Pragma("unroll") for (int j_ = 0; j_ < 2; ++j_) {                        \
        buf[par][4+2*j_]   = *(const bf16x8*)(pBh[j_] + kk_);                 \
        buf[par][4+2*j_+1] = *(const bf16x8*)(pBl[j_] + kk_); }               \
} while (0)

    LOADC(0, 0);
#pragma unroll
    for (int kc = 0; kc < NKC; ++kc) {
        const int cur = kc & 1;
        if (kc + 1 < NKC) LOADC(cur ^ 1, kc + 1);   // prefetch next chunk

#pragma unroll
        for (int i = 0; i < 2; ++i)
#pragma unroll
            for (int j = 0; j < 2; ++j) {
                const bf16x8 ah = buf[cur][2*i],   al = buf[cur][2*i+1];
                const bf16x8 bh = buf[cur][4+2*j], bl = buf[cur][4+2*j+1];
                acc[i][j] = __builtin_amdgcn_mfma_f32_16x16x32_bf16(ah, bh, acc[i][j], 0, 0, 0);
                acc[i][j] = __builtin_amdgcn_mfma_f32_16x16x32_bf16(ah, bl, acc[i][j], 0, 0, 0);
                acc[i][j] = __builtin_amdgcn_mfma_f32_16x16x32_bf16(al, bh, acc[i][j], 0, 0, 0);
            }
    }
#undef LOADC

    __syncthreads();   // sk zeroed + lh1/lh2 ready (first barrier in kernel)

    // Scatter (signs pre-folded): C/D layout col=lane&15, row=quad*4+reg.
#pragma unroll
    for (int i = 0; i < 2; ++i) {
        const int lr0 = wr + i * 16 + quad * 4;
#pragma unroll
        for (int j = 0; j < 2; ++j) {
            const int h2v = lh2[wc + j * 16 + l15];
#pragma unroll
            for (int rg = 0; rg < 4; ++rg) {
                const int bin = (lh1[lr0 + rg] + h2v) & (PROJ - 1);
                atomicAdd(&sk[bin], acc[i][j][rg]);   // ds_add_f32
            }
        }
    }
    __syncthreads();

    // Dump private sketch to ws.
    float4* dst = (float4*)(ws + (size_t)blk * PROJ);
    const float4* src = (const float4*)sk;
    for (int i = tid; i < PROJ / 4; i += 512) dst[i] = src[i];
}

__device__ __forceinline__ float ssqrt(float s) {
    const float m = sqrtf(fabsf(s) + 1e-8f);
    return (s > 0.f) ? m : (s < 0.f ? -m : 0.f);   // sign(0)=0
}

// ---------------------------------------------------------------------------
// Kernel 2: per-batch finalize. grid = 16 x 512. Sum 32 partials/bin,
// signed sqrt, ssq shuffle-reduce, normalize, single y write.
// Partial block for (b, t): ((b&1)<<8) | (t<<3) | (b>>1), t in [0,32).
// ---------------------------------------------------------------------------
__global__ __launch_bounds__(512)
void cbp_finalize(const float* __restrict__ ws, float* __restrict__ y) {
    __shared__ float red[8];
    const int b   = blockIdx.x;
    const int tid = threadIdx.x;
    const int pbase = ((b & 1) << 8) | (b >> 1);   // physical partial base

    float4 ov[4];
    float ssq = 0.f;
#pragma unroll
    for (int g = 0; g < 4; ++g) {
        const int f4 = tid + 512 * g;              // float4 index in [0,2048)
        float4 s = {0.f, 0.f, 0.f, 0.f};
#pragma unroll
        for (int t = 0; t < 32; ++t) {
            const float4 v =
                ((const float4*)(ws + (size_t)(pbase | (t << 3)) * PROJ))[f4];
            s.x += v.x; s.y += v.y; s.z += v.z; s.w += v.w;
        }
        float4 o;
        o.x = ssqrt(s.x); o.y = ssqrt(s.y); o.z = ssqrt(s.z); o.w = ssqrt(s.w);
        ov[g] = o;
        ssq += o.x * o.x + o.y * o.y + o.z * o.z + o.w * o.w;
    }

    float v = ssq;
#pragma unroll
    for (int off = 32; off >= 1; off >>= 1) v += __shfl_xor(v, off, 64);
    if ((tid & 63) == 0) red[tid >> 6] = v;
    __syncthreads();
    float tot = 0.f;
#pragma unroll
    for (int w = 0; w < 8; ++w) tot += red[w];
    const float inv = 1.0f / fmaxf(sqrtf(tot), 1e-12f);

    float4* yp = (float4*)(y + (size_t)b * PROJ);
#pragma unroll
    for (int g = 0; g < 4; ++g) {
        float4 o = ov[g];
        o.x *= inv; o.y *= inv; o.z *= inv; o.w *= inv;
        yp[tid + 512 * g] = o;
    }
}

// ---------------------------------------------------------------------------
extern "C" void kernel_launch(void* const* d_in, const int* in_sizes, int n_in,
                              void* d_out, int out_size, void* d_ws, size_t ws_size,
                              hipStream_t stream) {
    const float* x  = (const float*)d_in[0];
    const float* s1 = (const float*)d_in[1];
    const float* s2 = (const float*)d_in[2];
    const int*   h1 = (const int*)d_in[3];
    const int*   h2 = (const int*)d_in[4];
    float* y  = (float*)d_out;                     // [16, 8192]
    float* ws = (float*)d_ws;

    // ws map: [0, 16MB) 512 partial sketches; then 4 split-bf16 arrays.
    short* X1h = (short*)(ws + (size_t)512 * PROJ);
    short* X1l = X1h + (size_t)NB * NC * KP;
    short* X2h = X1l + (size_t)NB * NC * KP;
    short* X2l = X2h + (size_t)NB * NC * KP;

    hipLaunchKernelGGL(cbp_convert, dim3(896), dim3(256), 0, stream,
                       x, s1, s2, X1h, X1l, X2h, X2l);
    hipLaunchKernelGGL(cbp_gram, dim3(512), dim3(512), 0, stream,
                       X1h, X1l, X2h, X2l, h1, h2, ws);
    hipLaunchKernelGGL(cbp_finalize, dim3(16), dim3(512), 0, stream, ws, y);
}

// Round 8
// 109.584 us; speedup vs baseline: 1.0775x; 1.0775x over previous
//
#include <hip/hip_runtime.h>
#include <math.h>

#define PROJ 8192
#define NB   16
#define NC   512
#define HW   196    // 14*14
#define NKC  7      // K chunks of 32 (196 zero-padded to 224)
#define LST  40     // LDS row stride in bf16 elems (80 B: b128-aligned, 2-way banks = free)

typedef __attribute__((ext_vector_type(8))) short bf16x8;   // MFMA A/B frag
typedef __attribute__((ext_vector_type(4))) short short4v;
typedef __attribute__((ext_vector_type(4))) float f32x4;    // MFMA C/D frag

__device__ __forceinline__ unsigned bf16_rne(float f) {
    unsigned u = __builtin_bit_cast(unsigned, f);
    return (u + 0x7fffu + ((u >> 16) & 1u)) >> 16;
}

// ---------------------------------------------------------------------------
// Kernel 1: split-bf16 MFMA Gram (128x128 tile) + scatter into private LDS
// sketch -> global atomicAdd into per-batch sketch (512 KB total, L2-resident).
// Inner loop VERBATIM from the session-best 103.8us baseline (R0): LDS-staged,
// double-buffered prefetch, signs folded into staged bf16.
// grid = 256 blocks x 512 threads (8 waves = 2/SIMD).
//   block -> (batch,tile): b = 2*(blk&7) + (blk>>7), tile = (blk>>3)&15
// ---------------------------------------------------------------------------
__global__ __launch_bounds__(512, 2)
void cbp_gram_mfma(const float* __restrict__ x,
                   const float* __restrict__ s1,
                   const float* __restrict__ s2,
                   const int*   __restrict__ h1,
                   const int*   __restrict__ h2,
                   float* __restrict__ gsk) {
    __shared__ float sk[PROJ];         // 32 KB private sketch
    __shared__ short Ah[128 * LST];    // 10 KB each
    __shared__ short Al[128 * LST];
    __shared__ short Bh[128 * LST];
    __shared__ short Bl[128 * LST];
    __shared__ int   lh1[128], lh2[128];
    __shared__ float lsA[128], lsB[128];

    const int tid = threadIdx.x;
    const int blk = blockIdx.x;
    const int b    = 2 * (blk & 7) + (blk >> 7);   // XCD-pinned batch
    const int tile = (blk >> 3) & 15;
    const int I = tile >> 2, J = tile & 3;
    const int c1base = I * 128;
    const int c2base = J * 128;

    const int lane = tid & 63;
    const int wave = tid >> 6;         // 0..7
    const int quad = lane >> 4;
    const int l15  = lane & 15;
    const int wr   = (wave >> 1) * 32; // wave's 32x64 sub-tile
    const int wc   = (wave & 1) * 64;

    for (int i = tid; i < PROJ; i += 512) sk[i] = 0.f;
    if (tid < 128) {
        lh1[tid] = h1[c1base + tid];  lsA[tid] = s1[c1base + tid];
        lh2[tid] = h2[c2base + tid];  lsB[tid] = s2[c2base + tid];
    }

    const float* xa = x + ((size_t)b * NC + c1base) * HW;
    const float* xb = x + ((size_t)b * NC + c2base) * HW;

    f32x4 acc[2][4];
#pragma unroll
    for (int i = 0; i < 2; ++i)
#pragma unroll
        for (int j = 0; j < 4; ++j) acc[i][j] = (f32x4){0.f, 0.f, 0.f, 0.f};

    // Staging assignment: thread handles rows sr0 and sr0+64, float4 slot sq.
    const int sr0 = tid >> 3;          // 0..63
    const int sq  = tid & 7;           // 0..7

    float4 pa[2], pb[2];
    {   // prologue: load chunk 0
        const int kk = 4 * sq;
        const bool ok = (kk + 3 < HW);
#pragma unroll
        for (int h = 0; h < 2; ++h) {
            const int r = sr0 + 64 * h;
            pa[h] = ok ? *(const float4*)&xa[r * HW + kk] : (float4){0.f,0.f,0.f,0.f};
            pb[h] = ok ? *(const float4*)&xb[r * HW + kk] : (float4){0.f,0.f,0.f,0.f};
        }
    }

    for (int kc = 0; kc < NKC; ++kc) {
        __syncthreads();               // LDS free; also covers lh/ls on kc==0
        // Convert + store current chunk (signs folded; exact for +-1).
#pragma unroll
        for (int h = 0; h < 2; ++h) {
            const int r = sr0 + 64 * h;
            const float sA = lsA[r], sB = lsB[r];
            const float fa[4] = {pa[h].x*sA, pa[h].y*sA, pa[h].z*sA, pa[h].w*sA};
            const float fb[4] = {pb[h].x*sB, pb[h].y*sB, pb[h].z*sB, pb[h].w*sB};
            short4v ah, al, bh, bl;
#pragma unroll
            for (int c = 0; c < 4; ++c) {
                const unsigned ha_ = bf16_rne(fa[c]);
                ah[c] = (short)ha_;
                al[c] = (short)bf16_rne(fa[c] - __builtin_bit_cast(float, ha_ << 16));
                const unsigned hb_ = bf16_rne(fb[c]);
                bh[c] = (short)hb_;
                bl[c] = (short)bf16_rne(fb[c] - __builtin_bit_cast(float, hb_ << 16));
            }
            *(short4v*)&Ah[r * LST + 4 * sq] = ah;
            *(short4v*)&Al[r * LST + 4 * sq] = al;
            *(short4v*)&Bh[r * LST + 4 * sq] = bh;
            *(short4v*)&Bl[r * LST + 4 * sq] = bl;
        }
        // Prefetch next chunk while this chunk computes.
        if (kc + 1 < NKC) {
            const int kk = (kc + 1) * 32 + 4 * sq;
            const bool ok = (kk + 3 < HW);
#pragma unroll
            for (int h = 0; h < 2; ++h) {
                const int r = sr0 + 64 * h;
                pa[h] = ok ? *(const float4*)&xa[r * HW + kk] : (float4){0.f,0.f,0.f,0.f};
                pb[h] = ok ? *(const float4*)&xb[r * HW + kk] : (float4){0.f,0.f,0.f,0.f};
            }
        }
        __syncthreads();

        bf16x8 ahf[2], alf[2], bhf[4], blf[4];
#pragma unroll
        for (int i = 0; i < 2; ++i) {
            const int ra = wr + i * 16 + l15;
            ahf[i] = *(const bf16x8*)&Ah[ra * LST + quad * 8];
            alf[i] = *(const bf16x8*)&Al[ra * LST + quad * 8];
        }
#pragma unroll
        for (int j = 0; j < 4; ++j) {
            const int rb = wc + j * 16 + l15;
            bhf[j] = *(const bf16x8*)&Bh[rb * LST + quad * 8];
            blf[j] = *(const bf16x8*)&Bl[rb * LST + quad * 8];
        }
#pragma unroll
        for (int i = 0; i < 2; ++i)
#pragma unroll
            for (int j = 0; j < 4; ++j) {
                acc[i][j] = __builtin_amdgcn_mfma_f32_16x16x32_bf16(ahf[i], bhf[j], acc[i][j], 0, 0, 0);
                acc[i][j] = __builtin_amdgcn_mfma_f32_16x16x32_bf16(ahf[i], blf[j], acc[i][j], 0, 0, 0);
                acc[i][j] = __builtin_amdgcn_mfma_f32_16x16x32_bf16(alf[i], bhf[j], acc[i][j], 0, 0, 0);
            }
    }
    __syncthreads();

    // Scatter (signs pre-folded): C/D layout col=lane&15, row=quad*4+reg.
#pragma unroll
    for (int i = 0; i < 2; ++i) {
        const int lr0 = wr + i * 16 + quad * 4;
#pragma unroll
        for (int j = 0; j < 4; ++j) {
            const int h2v = lh2[wc + j * 16 + l15];
#pragma unroll
            for (int rg = 0; rg < 4; ++rg) {
                const int bin = (lh1[lr0 + rg] + h2v) & (PROJ - 1);
                atomicAdd(&sk[bin], acc[i][j][rg]);   // ds_add_f32
            }
        }
    }
    __syncthreads();

    // Accumulate private sketch into the batch's global sketch (coalesced
    // global_atomic_add_f32; <=16 writers/bin; gsk zeroed by hipMemsetAsync).
    float* gs = gsk + (size_t)b * PROJ;
    for (int i = tid; i < PROJ; i += 512) atomicAdd(&gs[i], sk[i]);
}

__device__ __forceinline__ float ssqrt(float s) {
    const float m = sqrtf(fabsf(s) + 1e-8f);
    return (s > 0.f) ? m : (s < 0.f ? -m : 0.f);   // sign(0)=0
}

// ---------------------------------------------------------------------------
// Kernel 2: per-batch finalize. grid = 16 x 512. Read the batch sketch
// (512 KB total, L2-hot from the atomics), signed sqrt, ssq shuffle-reduce,
// normalize, single y write.
// ---------------------------------------------------------------------------
__global__ __launch_bounds__(512)
void cbp_finalize(const float* __restrict__ gsk, float* __restrict__ y) {
    __shared__ float red[8];
    const int b   = blockIdx.x;
    const int tid = threadIdx.x;
    const float4* gp = (const float4*)(gsk + (size_t)b * PROJ);

    float4 ov[4];
    float ssq = 0.f;
#pragma unroll
    for (int g = 0; g < 4; ++g) {
        const float4 s = gp[tid + 512 * g];
        float4 o;
        o.x = ssqrt(s.x); o.y = ssqrt(s.y); o.z = ssqrt(s.z); o.w = ssqrt(s.w);
        ov[g] = o;
        ssq += o.x * o.x + o.y * o.y + o.z * o.z + o.w * o.w;
    }

    float v = ssq;
#pragma unroll
    for (int off = 32; off >= 1; off >>= 1) v += __shfl_xor(v, off, 64);
    if ((tid & 63) == 0) red[tid >> 6] = v;
    __syncthreads();
    float tot = 0.f;
#pragma unroll
    for (int w = 0; w < 8; ++w) tot += red[w];
    const float inv = 1.0f / fmaxf(sqrtf(tot), 1e-12f);

    float4* yp = (float4*)(y + (size_t)b * PROJ);
#pragma unroll
    for (int g = 0; g < 4; ++g) {
        float4 o = ov[g];
        o.x *= inv; o.y *= inv; o.z *= inv; o.w *= inv;
        yp[tid + 512 * g] = o;
    }
}

// ---------------------------------------------------------------------------
extern "C" void kernel_launch(void* const* d_in, const int* in_sizes, int n_in,
                              void* d_out, int out_size, void* d_ws, size_t ws_size,
                              hipStream_t stream) {
    const float* x  = (const float*)d_in[0];
    const float* s1 = (const float*)d_in[1];
    const float* s2 = (const float*)d_in[2];
    const int*   h1 = (const int*)d_in[3];
    const int*   h2 = (const int*)d_in[4];
    float* y   = (float*)d_out;                    // [16, 8192]
    float* gsk = (float*)d_ws;                     // 16 batch sketches (512 KB)

    hipMemsetAsync(gsk, 0, (size_t)NB * PROJ * sizeof(float), stream);
    hipLaunchKernelGGL(cbp_gram_mfma, dim3(256), dim3(512), 0, stream,
                       x, s1, s2, h1, h2, gsk);
    hipLaunchKernelGGL(cbp_finalize, dim3(16), dim3(512), 0, stream, gsk, y);
}

// Round 9
// 103.900 us; speedup vs baseline: 1.1365x; 1.0547x over previous
//
#include <hip/hip_runtime.h>
#include <math.h>

#define PROJ 8192
#define NB   16
#define NC   512
#define HW   196    // 14*14
#define NKC  7      // K chunks of 32 (196 zero-padded to 224)
#define LST  40     // LDS row stride in bf16 elems (80 B: b128-aligned, 2-way banks = free)

typedef __attribute__((ext_vector_type(8))) short bf16x8;   // MFMA A/B frag
typedef __attribute__((ext_vector_type(4))) short short4v;
typedef __attribute__((ext_vector_type(4))) float f32x4;    // MFMA C/D frag

__device__ __forceinline__ unsigned bf16_rne(float f) {
    unsigned u = __builtin_bit_cast(unsigned, f);
    return (u + 0x7fffu + ((u >> 16) & 1u)) >> 16;
}

// ---------------------------------------------------------------------------
// Kernel 1: split-bf16 MFMA Gram (128x128 tile) + scatter into private LDS
// sketch -> global atomicAdd into per-batch sketch (512 KB, L2-resident).
// Arithmetic identical to the session-best baseline. ONE structural change vs
// R8: 1024 threads/block (16 waves -> 4 waves/SIMD, was 2). R8 counters
// showed 90% stall at 2 waves/SIMD lockstep (MfmaUtil 4.1%, VALUBusy 9.4%,
// resource floor ~5us vs 45us measured): doubling resident waves per SIMD
// halves every exposed latency. Per wave: 32x32 sub-tile (4x4 wave grid).
// grid = 256 blocks x 1024 threads.
//   block -> (batch,tile): b = 2*(blk&7) + (blk>>7), tile = (blk>>3)&15
// ---------------------------------------------------------------------------
__global__ __launch_bounds__(1024, 4)
void cbp_gram_mfma(const float* __restrict__ x,
                   const float* __restrict__ s1,
                   const float* __restrict__ s2,
                   const int*   __restrict__ h1,
                   const int*   __restrict__ h2,
                   float* __restrict__ gsk) {
    __shared__ float sk[PROJ];         // 32 KB private sketch
    __shared__ short Ah[128 * LST];    // 10 KB each
    __shared__ short Al[128 * LST];
    __shared__ short Bh[128 * LST];
    __shared__ short Bl[128 * LST];
    __shared__ int   lh1[128], lh2[128];
    __shared__ float lsA[128], lsB[128];

    const int tid = threadIdx.x;
    const int blk = blockIdx.x;
    const int b    = 2 * (blk & 7) + (blk >> 7);   // XCD-pinned batch
    const int tile = (blk >> 3) & 15;
    const int I = tile >> 2, J = tile & 3;
    const int c1base = I * 128;
    const int c2base = J * 128;

    const int lane = tid & 63;
    const int wave = tid >> 6;         // 0..15
    const int quad = lane >> 4;
    const int l15  = lane & 15;
    const int wr   = (wave >> 2) * 32; // wave's 32x32 sub-tile
    const int wc   = (wave & 3) * 32;

    for (int i = tid; i < PROJ; i += 1024) sk[i] = 0.f;
    if (tid < 128) {
        lh1[tid] = h1[c1base + tid];  lsA[tid] = s1[c1base + tid];
        lh2[tid] = h2[c2base + tid];  lsB[tid] = s2[c2base + tid];
    }

    const float* xa = x + ((size_t)b * NC + c1base) * HW;
    const float* xb = x + ((size_t)b * NC + c2base) * HW;

    f32x4 acc[2][2];
#pragma unroll
    for (int i = 0; i < 2; ++i)
#pragma unroll
        for (int j = 0; j < 2; ++j) acc[i][j] = (f32x4){0.f, 0.f, 0.f, 0.f};

    // Staging: thread handles row sr0 (0..127), float4 slot sq (0..7).
    const int sr0 = tid >> 3;          // 0..127
    const int sq  = tid & 7;           // 0..7

    float4 pa, pb;
    {   // prologue: load chunk 0
        const int kk = 4 * sq;
        const bool ok = (kk + 3 < HW);
        pa = ok ? *(const float4*)&xa[sr0 * HW + kk] : (float4){0.f,0.f,0.f,0.f};
        pb = ok ? *(const float4*)&xb[sr0 * HW + kk] : (float4){0.f,0.f,0.f,0.f};
    }

    for (int kc = 0; kc < NKC; ++kc) {
        __syncthreads();               // LDS free; also covers lh/ls on kc==0
        // Convert + store current chunk (signs folded; exact for +-1).
        {
            const float sA = lsA[sr0], sB = lsB[sr0];
            const float fa[4] = {pa.x*sA, pa.y*sA, pa.z*sA, pa.w*sA};
            const float fb[4] = {pb.x*sB, pb.y*sB, pb.z*sB, pb.w*sB};
            short4v ah, al, bh, bl;
#pragma unroll
            for (int c = 0; c < 4; ++c) {
                const unsigned ha_ = bf16_rne(fa[c]);
                ah[c] = (short)ha_;
                al[c] = (short)bf16_rne(fa[c] - __builtin_bit_cast(float, ha_ << 16));
                const unsigned hb_ = bf16_rne(fb[c]);
                bh[c] = (short)hb_;
                bl[c] = (short)bf16_rne(fb[c] - __builtin_bit_cast(float, hb_ << 16));
            }
            *(short4v*)&Ah[sr0 * LST + 4 * sq] = ah;
            *(short4v*)&Al[sr0 * LST + 4 * sq] = al;
            *(short4v*)&Bh[sr0 * LST + 4 * sq] = bh;
            *(short4v*)&Bl[sr0 * LST + 4 * sq] = bl;
        }
        // Prefetch next chunk while this chunk computes.
        if (kc + 1 < NKC) {
            const int kk = (kc + 1) * 32 + 4 * sq;
            const bool ok = (kk + 3 < HW);
            pa = ok ? *(const float4*)&xa[sr0 * HW + kk] : (float4){0.f,0.f,0.f,0.f};
            pb = ok ? *(const float4*)&xb[sr0 * HW + kk] : (float4){0.f,0.f,0.f,0.f};
        }
        __syncthreads();

        bf16x8 ahf[2], alf[2], bhf[2], blf[2];
#pragma unroll
        for (int i = 0; i < 2; ++i) {
            const int ra = wr + i * 16 + l15;
            ahf[i] = *(const bf16x8*)&Ah[ra * LST + quad * 8];
            alf[i] = *(const bf16x8*)&Al[ra * LST + quad * 8];
        }
#pragma unroll
        for (int j = 0; j < 2; ++j) {
            const int rb = wc + j * 16 + l15;
            bhf[j] = *(const bf16x8*)&Bh[rb * LST + quad * 8];
            blf[j] = *(const bf16x8*)&Bl[rb * LST + quad * 8];
        }
#pragma unroll
        for (int i = 0; i < 2; ++i)
#pragma unroll
            for (int j = 0; j < 2; ++j) {
                acc[i][j] = __builtin_amdgcn_mfma_f32_16x16x32_bf16(ahf[i], bhf[j], acc[i][j], 0, 0, 0);
                acc[i][j] = __builtin_amdgcn_mfma_f32_16x16x32_bf16(ahf[i], blf[j], acc[i][j], 0, 0, 0);
                acc[i][j] = __builtin_amdgcn_mfma_f32_16x16x32_bf16(alf[i], bhf[j], acc[i][j], 0, 0, 0);
            }
    }
    __syncthreads();

    // Scatter (signs pre-folded): C/D layout col=lane&15, row=quad*4+reg.
#pragma unroll
    for (int i = 0; i < 2; ++i) {
        const int lr0 = wr + i * 16 + quad * 4;
#pragma unroll
        for (int j = 0; j < 2; ++j) {
            const int h2v = lh2[wc + j * 16 + l15];
#pragma unroll
            for (int rg = 0; rg < 4; ++rg) {
                const int bin = (lh1[lr0 + rg] + h2v) & (PROJ - 1);
                atomicAdd(&sk[bin], acc[i][j][rg]);   // ds_add_f32
            }
        }
    }
    __syncthreads();

    // Accumulate private sketch into the batch's global sketch (coalesced
    // global_atomic_add_f32; <=16 writers/bin; gsk zeroed by hipMemsetAsync).
    float* gs = gsk + (size_t)b * PROJ;
    for (int i = tid; i < PROJ; i += 1024) atomicAdd(&gs[i], sk[i]);
}

__device__ __forceinline__ float ssqrt(float s) {
    const float m = sqrtf(fabsf(s) + 1e-8f);
    return (s > 0.f) ? m : (s < 0.f ? -m : 0.f);   // sign(0)=0
}

// ---------------------------------------------------------------------------
// Kernel 2: per-batch finalize. grid = 16 x 512. Read the batch sketch
// (512 KB total, L2-hot from the atomics), signed sqrt, ssq shuffle-reduce,
// normalize, single y write.
// ---------------------------------------------------------------------------
__global__ __launch_bounds__(512)
void cbp_finalize(const float* __restrict__ gsk, float* __restrict__ y) {
    __shared__ float red[8];
    const int b   = blockIdx.x;
    const int tid = threadIdx.x;
    const float4* gp = (const float4*)(gsk + (size_t)b * PROJ);

    float4 ov[4];
    float ssq = 0.f;
#pragma unroll
    for (int g = 0; g < 4; ++g) {
        const float4 s = gp[tid + 512 * g];
        float4 o;
        o.x = ssqrt(s.x); o.y = ssqrt(s.y); o.z = ssqrt(s.z); o.w = ssqrt(s.w);
        ov[g] = o;
        ssq += o.x * o.x + o.y * o.y + o.z * o.z + o.w * o.w;
    }

    float v = ssq;
#pragma unroll
    for (int off = 32; off >= 1; off >>= 1) v += __shfl_xor(v, off, 64);
    if ((tid & 63) == 0) red[tid >> 6] = v;
    __syncthreads();
    float tot = 0.f;
#pragma unroll
    for (int w = 0; w < 8; ++w) tot += red[w];
    const float inv = 1.0f / fmaxf(sqrtf(tot), 1e-12f);

    float4* yp = (float4*)(y + (size_t)b * PROJ);
#pragma unroll
    for (int g = 0; g < 4; ++g) {
        float4 o = ov[g];
        o.x *= inv; o.y *= inv; o.z *= inv; o.w *= inv;
        yp[tid + 512 * g] = o;
    }
}

// ---------------------------------------------------------------------------
extern "C" void kernel_launch(void* const* d_in, const int* in_sizes, int n_in,
                              void* d_out, int out_size, void* d_ws, size_t ws_size,
                              hipStream_t stream) {
    const float* x  = (const float*)d_in[0];
    const float* s1 = (const float*)d_in[1];
    const float* s2 = (const float*)d_in[2];
    const int*   h1 = (const int*)d_in[3];
    const int*   h2 = (const int*)d_in[4];
    float* y   = (float*)d_out;                    // [16, 8192]
    float* gsk = (float*)d_ws;                     // 16 batch sketches (512 KB)

    hipMemsetAsync(gsk, 0, (size_t)NB * PROJ * sizeof(float), stream);
    hipLaunchKernelGGL(cbp_gram_mfma, dim3(256), dim3(1024), 0, stream,
                       x, s1, s2, h1, h2, gsk);
    hipLaunchKernelGGL(cbp_finalize, dim3(16), dim3(512), 0, stream, gsk, y);
}